// Round 8
// baseline (211.406 us; speedup 1.0000x reference)
//
#include <hip/hip_runtime.h>
#include <hip/hip_cooperative_groups.h>
#include <hip/hip_bf16.h>

namespace cg = cooperative_groups;

#define NN 8192   // nodes
#define NE 8192   // edges
#define CC 256    // channels
#define CAP 128   // max nnz per row/col (mean ~34, sigma ~5.7)
#define NB 256    // blocks (1/CU)
#define NTH 1024  // threads/block (16 waves)

typedef __attribute__((ext_vector_type(8))) short bf16x8;
typedef __attribute__((ext_vector_type(8))) unsigned short u16x8;
typedef __attribute__((ext_vector_type(4))) float f32x4;

static __device__ __forceinline__ ushort f2b(float f) {       // RNE f32->bf16
    unsigned u = __float_as_uint(f);
    return (ushort)((u + 0x7fffu + ((u >> 16) & 1u)) >> 16);
}
static __device__ __forceinline__ float b2f(ushort u) {
    return __uint_as_float((unsigned)u << 16);
}

// Single persistent cooperative kernel; phases separated by grid.sync().
__global__ __launch_bounds__(NTH, 1) void fused_all(
        const float* __restrict__ B, const float* __restrict__ x0,
        const float* __restrict__ W,
        ushort* __restrict__ x0b, ushort* __restrict__ Wb,
        int* __restrict__ csr, int* __restrict__ row_cnt,
        int* __restrict__ col_cnt, int* __restrict__ csc,
        float* __restrict__ edge_wsum, ushort* __restrict__ m01s,
        float* __restrict__ out) {
    cg::grid_group grid = cg::this_grid();
    const int tid  = threadIdx.x;
    const int bid  = blockIdx.x;
    const int w    = tid >> 6;         // wave 0..15
    const int lane = tid & 63;
    const int half = lane >> 5;
    const int cl   = lane & 31;
    __shared__ int wcnt[16];
    __shared__ __align__(16) ushort xs[32][264];  // 16.5 KB; stride 264 -> free 2-way

    // ================= P0: zero counters, convert x0/W, scan B rows -> csr ===
    {
        int z = bid * NTH + tid;
        if (z < 2 * NE) col_cnt[z] = 0;            // col_cnt + edge_wsum (0 == 0.0f)
        int i = (bid * NTH + tid) * 8;             // x0: 2M elems, 8/thread
        f32x4 v0 = *(const f32x4*)(x0 + i);
        f32x4 v1 = *(const f32x4*)(x0 + i + 4);
        u16x8 u;
        u[0]=f2b(v0.x); u[1]=f2b(v0.y); u[2]=f2b(v0.z); u[3]=f2b(v0.w);
        u[4]=f2b(v1.x); u[5]=f2b(v1.y); u[6]=f2b(v1.z); u[7]=f2b(v1.w);
        *(u16x8*)(x0b + i) = u;
        if (bid < 8) {                             // W: 64K elems over 8 blocks
            f32x4 w0 = *(const f32x4*)(W + i);
            f32x4 w1 = *(const f32x4*)(W + i + 4);
            u16x8 uw;
            uw[0]=f2b(w0.x); uw[1]=f2b(w0.y); uw[2]=f2b(w0.z); uw[3]=f2b(w0.w);
            uw[4]=f2b(w1.x); uw[5]=f2b(w1.y); uw[6]=f2b(w1.z); uw[7]=f2b(w1.w);
            *(u16x8*)(Wb + i) = uw;
        }
    }
    int cnts[2];                                   // row counts kept in registers
    #pragma unroll 1
    for (int rr = 0; rr < 2; ++rr) {
        const int row = bid * 32 + w * 2 + rr;
        const f32x4* rp = (const f32x4*)(B + (size_t)row * NE);
        int* outp = csr + (size_t)row * CAP;
        if (lane == 0) wcnt[w] = 0;                // same-wave ds ops are in order
        #pragma unroll 1
        for (int it = 0; it < 32; ++it) {          // 32 x 1 KB/wave
            f32x4 v = rp[it * 64 + lane];
            float fs = v.x + v.y + v.z + v.w;      // binary entries: #nonzero
            if (__ballot(fs != 0.f)) {
                int m = (int)fs;
                int pos = 0;
                if (m) pos = atomicAdd(&wcnt[w], m);
                int e0 = (it * 64 + lane) * 4;
                if (v.x != 0.f) { if (pos < CAP) outp[pos] = e0;     ++pos; }
                if (v.y != 0.f) { if (pos < CAP) outp[pos] = e0 + 1; ++pos; }
                if (v.z != 0.f) { if (pos < CAP) outp[pos] = e0 + 2; ++pos; }
                if (v.w != 0.f) { if (pos < CAP) outp[pos] = e0 + 3; ++pos; }
            }
        }
        int c = wcnt[w];                           // read after same-wave atomics
        c = c < CAP ? c : CAP;
        cnts[rr] = c;
        if (lane == 0) row_cnt[row] = c;
    }
    grid.sync();
    // ================= P1: scatter csr -> csc + degree sums ==================
    #pragma unroll 1
    for (int rr = 0; rr < 2; ++rr) {
        const int row = bid * 32 + w * 2 + rr;
        const int cnt = cnts[rr];
        const float deg = (float)cnt;
        const int* outp = csr + (size_t)row * CAP; // own-block rows: L2-hot
        for (int i = lane; i < cnt; i += 64) {
            int e = outp[i];
            int pos = atomicAdd(&col_cnt[e], 1);
            if (pos < CAP) csc[(size_t)e * CAP + pos] = row;
            atomicAdd(&edge_wsum[e], deg);         // integer-valued: exact
        }
    }
    grid.sync();
    // ================= P2: edge aggregation -> m01s ==========================
    #pragma unroll 1
    for (int ee = 0; ee < 2; ++ee) {
        const int e = bid * 32 + ee * 16 + w;
        int cnt = col_cnt[e]; if (cnt > CAP) cnt = CAP;
        const float er = rsqrtf(edge_wsum[e] / (float)cnt);
        const int* cp = csc + (size_t)e * CAP;
        const int idx = cp[lane];
        const ushort* xb = x0b + cl * 8;
        float a0[8] = {}, a1[8] = {};
        const int lim = cnt < 64 ? cnt : 64;
        int i = 0;
        for (; i + 8 <= lim; i += 8) {
            int n0 = __shfl(idx, i + half);
            int n1 = __shfl(idx, i + 2 + half);
            int n2 = __shfl(idx, i + 4 + half);
            int n3 = __shfl(idx, i + 6 + half);
            u16x8 r0 = *(const u16x8*)(xb + (size_t)n0 * CC);
            u16x8 r1 = *(const u16x8*)(xb + (size_t)n1 * CC);
            u16x8 r2 = *(const u16x8*)(xb + (size_t)n2 * CC);
            u16x8 r3 = *(const u16x8*)(xb + (size_t)n3 * CC);
            #pragma unroll
            for (int c = 0; c < 8; ++c) {
                a0[c] += b2f(r0[c]); a1[c] += b2f(r1[c]);
                a0[c] += b2f(r2[c]); a1[c] += b2f(r3[c]);
            }
        }
        for (; i + 2 <= lim; i += 2) {
            int n0 = __shfl(idx, i + half);
            u16x8 r0 = *(const u16x8*)(xb + (size_t)n0 * CC);
            #pragma unroll
            for (int c = 0; c < 8; ++c) a0[c] += b2f(r0[c]);
        }
        if (i < lim) {
            int n0 = __shfl(idx, i);               // shfl before divergence
            if (half == 0) {
                u16x8 r0 = *(const u16x8*)(xb + (size_t)n0 * CC);
                #pragma unroll
                for (int c = 0; c < 8; ++c) a0[c] += b2f(r0[c]);
            }
        }
        if (cnt > 64 && half == 0) {               // vanishing probability
            for (int j = 64; j < cnt; ++j) {
                int n2 = cp[j];
                u16x8 r0 = *(const u16x8*)(xb + (size_t)n2 * CC);
                #pragma unroll
                for (int c = 0; c < 8; ++c) a0[c] += b2f(r0[c]);
            }
        }
        u16x8 r8;
        #pragma unroll
        for (int c = 0; c < 8; ++c) {
            float t = a0[c] + a1[c];
            t += __shfl_xor(t, 32);
            r8[c] = f2b(t * er);
        }
        if (half == 0) *(u16x8*)(m01s + (size_t)e * CC + cl * 8) = r8;
    }
    grid.sync();
    // ================= P3: node aggregation -> LDS, then fused GEMM ==========
    #pragma unroll 1
    for (int nn2 = 0; nn2 < 2; ++nn2) {
        const int n = bid * 32 + nn2 * 16 + w;
        const int cnt = row_cnt[n];
        const float nr = rsqrtf((float)cnt);
        const int* ep = csr + (size_t)n * CAP;
        const int idx = ep[lane];
        const ushort* mb = m01s + cl * 8;
        float a0[8] = {}, a1[8] = {};
        const int lim = cnt < 64 ? cnt : 64;
        int i = 0;
        for (; i + 8 <= lim; i += 8) {
            int e0 = __shfl(idx, i + half);
            int e1 = __shfl(idx, i + 2 + half);
            int e2 = __shfl(idx, i + 4 + half);
            int e3 = __shfl(idx, i + 6 + half);
            u16x8 r0 = *(const u16x8*)(mb + (size_t)e0 * CC);
            u16x8 r1 = *(const u16x8*)(mb + (size_t)e1 * CC);
            u16x8 r2 = *(const u16x8*)(mb + (size_t)e2 * CC);
            u16x8 r3 = *(const u16x8*)(mb + (size_t)e3 * CC);
            #pragma unroll
            for (int c = 0; c < 8; ++c) {
                a0[c] += b2f(r0[c]); a1[c] += b2f(r1[c]);
                a0[c] += b2f(r2[c]); a1[c] += b2f(r3[c]);
            }
        }
        for (; i + 2 <= lim; i += 2) {
            int e0 = __shfl(idx, i + half);
            u16x8 r0 = *(const u16x8*)(mb + (size_t)e0 * CC);
            #pragma unroll
            for (int c = 0; c < 8; ++c) a0[c] += b2f(r0[c]);
        }
        if (i < lim) {
            int e0 = __shfl(idx, i);
            if (half == 0) {
                u16x8 r0 = *(const u16x8*)(mb + (size_t)e0 * CC);
                #pragma unroll
                for (int c = 0; c < 8; ++c) a0[c] += b2f(r0[c]);
            }
        }
        if (cnt > 64 && half == 0) {
            for (int j = 64; j < cnt; ++j) {
                int e2 = ep[j];
                u16x8 r0 = *(const u16x8*)(mb + (size_t)e2 * CC);
                #pragma unroll
                for (int c = 0; c < 8; ++c) a0[c] += b2f(r0[c]);
            }
        }
        u16x8 x = *(const u16x8*)(x0b + (size_t)n * CC + cl * 8);
        const float s = 0.9f * nr;
        u16x8 r8;
        #pragma unroll
        for (int c = 0; c < 8; ++c) {
            float t = a0[c] + a1[c];
            t += __shfl_xor(t, 32);
            r8[c] = f2b(s * t + 0.1f * b2f(x[c]));
        }
        if (half == 0) *(u16x8*)(&xs[nn2 * 16 + w][cl * 8]) = r8;
    }
    __syncthreads();
    // MFMA epilogue: wave w owns col-strip [w*16, w*16+16) for both 16-row tiles.
    // A row=l&15, k=(l>>4)*8+e; B col=l&15; C/D col=l&15, row=(l>>4)*4+reg (m89).
    {
        const int lr = lane & 15, lk = lane >> 4;
        const int col = w * 16 + lr;
        #pragma unroll
        for (int rt = 0; rt < 2; ++rt) {
            f32x4 acc = {0.f, 0.f, 0.f, 0.f};
            #pragma unroll
            for (int kb = 0; kb < 8; ++kb) {
                bf16x8 a = *(const bf16x8*)(&xs[rt * 16 + lr][kb * 32 + lk * 8]);
                bf16x8 b = *(const bf16x8*)(Wb + (size_t)(w * 16 + lr) * CC + kb * 32 + lk * 8);
                acc = __builtin_amdgcn_mfma_f32_16x16x32_bf16(a, b, acc, 0, 0, 0);
            }
            #pragma unroll
            for (int r = 0; r < 4; ++r) {
                int row = rt * 16 + lk * 4 + r;
                float sk = b2f(xs[row][col]);
                out[(size_t)(bid * 32 + row) * CC + col] = 0.5f * sk + 0.5f * acc[r];
            }
        }
    }
}

// ---- launch -----------------------------------------------------------------
extern "C" void kernel_launch(void* const* d_in, const int* in_sizes, int n_in,
                              void* d_out, int out_size, void* d_ws, size_t ws_size,
                              hipStream_t stream) {
    const float* x0 = (const float*)d_in[0];
    const float* B  = (const float*)d_in[1];
    const float* W  = (const float*)d_in[2];
    float* out = (float*)d_out;

    char* ws = (char*)d_ws;
    const size_t need = (16ull << 20) + (512ull << 10);
    if (ws_size < need) return;

    int*    csr       = (int*)(ws);                    // 4 MB
    int*    csc       = (int*)(ws + (4ull << 20));     // 4 MB
    ushort* m01s      = (ushort*)(ws + (8ull << 20));  // 4 MB (bf16)
    ushort* x0b       = (ushort*)(ws + (12ull << 20)); // 4 MB (bf16)
    ushort* Wb        = (ushort*)(ws + (16ull << 20)); // 128 KB (bf16)
    int*    row_cnt   = (int*)(ws + (16ull << 20) + (256u << 10)); // 32 KB
    int*    col_cnt   = row_cnt + NN;                  // 32 KB (zeroed in P0)
    float*  edge_wsum = (float*)(col_cnt + NE);        // 32 KB (zeroed in P0)

    void* args[] = {
        (void*)&B, (void*)&x0, (void*)&W,
        (void*)&x0b, (void*)&Wb,
        (void*)&csr, (void*)&row_cnt, (void*)&col_cnt, (void*)&csc,
        (void*)&edge_wsum, (void*)&m01s, (void*)&out
    };
    hipLaunchCooperativeKernel((const void*)fused_all, dim3(NB), dim3(NTH),
                               args, 0, stream);
}

// Round 9
// 147.330 us; speedup vs baseline: 1.4349x; 1.4349x over previous
//
#include <hip/hip_runtime.h>
#include <hip/hip_bf16.h>

#define NN 8192   // nodes
#define NE 8192   // edges
#define CC 256    // channels
#define CAP 128   // max nnz per row/col (mean ~34, sigma ~5.7)
#define PNL 32    // edges per panel block

typedef __attribute__((ext_vector_type(8))) short bf16x8;
typedef __attribute__((ext_vector_type(8))) unsigned short u16x8;
typedef __attribute__((ext_vector_type(4))) float f32x4;

static __device__ __forceinline__ ushort f2b(float f) {       // RNE f32->bf16
    unsigned u = __float_as_uint(f);
    return (ushort)((u + 0x7fffu + ((u >> 16) & 1u)) >> 16);
}
static __device__ __forceinline__ float b2f(ushort u) {
    return __uint_as_float((unsigned)u << 16);
}

// ---- K0: convert x0/W -> bf16, zero row_cnt --------------------------------
__global__ __launch_bounds__(256) void k0_convert(const float* __restrict__ x0,
                                                  const float* __restrict__ W,
                                                  ushort* __restrict__ x0b,
                                                  ushort* __restrict__ Wb,
                                                  int* __restrict__ row_cnt) {
    const int t = blockIdx.x * 256 + threadIdx.x;
    const int i = t * 8;
    f32x4 v0 = *(const f32x4*)(x0 + i);
    f32x4 v1 = *(const f32x4*)(x0 + i + 4);
    u16x8 u;
    u[0]=f2b(v0.x); u[1]=f2b(v0.y); u[2]=f2b(v0.z); u[3]=f2b(v0.w);
    u[4]=f2b(v1.x); u[5]=f2b(v1.y); u[6]=f2b(v1.z); u[7]=f2b(v1.w);
    *(u16x8*)(x0b + i) = u;
    if (i < CC * CC) {
        f32x4 w0 = *(const f32x4*)(W + i);
        f32x4 w1 = *(const f32x4*)(W + i + 4);
        u16x8 uw;
        uw[0]=f2b(w0.x); uw[1]=f2b(w0.y); uw[2]=f2b(w0.z); uw[3]=f2b(w0.w);
        uw[4]=f2b(w1.x); uw[5]=f2b(w1.y); uw[6]=f2b(w1.z); uw[7]=f2b(w1.w);
        *(u16x8*)(Wb + i) = uw;
    }
    if (t < NN) row_cnt[t] = 0;
}

// ---- K1': column-panel scan + in-block edge aggregation --------------------
// Block owns 32 edges (a 128-B column stripe of B). Scan all rows: per wave-
// instruction 8 rows x 32 cols (float4, 1 KB, cacheline-aligned). Nonzeros:
// csr slot via atomicAdd(row_cnt) (row_cnt doubles as degree), edge member
// lists in LDS. Then the SAME block aggregates its 32 edges from LDS indices:
// m01s_raw[e] = sum_n x0b[n]  (er scaling deferred to K5).
__global__ __launch_bounds__(1024) void k1_panel(const float* __restrict__ B,
                                                 const ushort* __restrict__ x0b,
                                                 int* __restrict__ csr,
                                                 int* __restrict__ row_cnt,
                                                 int* __restrict__ col_cnt,
                                                 int* __restrict__ csc,
                                                 ushort* __restrict__ m01s) {
    __shared__ int ecnt[PNL];
    __shared__ int cloc[PNL][CAP];
    const int tid = threadIdx.x, w = tid >> 6, lane = tid & 63;
    const int e0 = blockIdx.x * PNL;
    if (tid < PNL) ecnt[tid] = 0;
    __syncthreads();
    const int lr = lane >> 3;            // row-in-group 0..7
    const int lc = (lane & 7) * 4;       // col offset 0,4,..,28
    const float* Bp = B + e0 + lc;
    const int rbase = w * 8 + lr;
    f32x4 buf[4];
    #pragma unroll
    for (int p = 0; p < 4; ++p)
        buf[p] = *(const f32x4*)(Bp + (size_t)(p * 128 + rbase) * NE);
    #pragma unroll 1
    for (int it = 0; it < 64; ++it) {    // 64 x 128 rows
        f32x4 v = buf[it & 3];
        if (it + 4 < 64)
            buf[it & 3] = *(const f32x4*)(Bp + (size_t)((it + 4) * 128 + rbase) * NE);
        float fs = v.x + v.y + v.z + v.w;            // binary: #nonzero
        if (__ballot(fs != 0.f)) {
            if (fs != 0.f) {
                const int row = it * 128 + rbase;
                int p0 = atomicAdd(&row_cnt[row], (int)fs);
                if (v.x != 0.f) { if (p0 < CAP) csr[(size_t)row*CAP+p0] = e0+lc;   ++p0;
                                  int q = atomicAdd(&ecnt[lc],   1); if (q < CAP) cloc[lc][q]   = row; }
                if (v.y != 0.f) { if (p0 < CAP) csr[(size_t)row*CAP+p0] = e0+lc+1; ++p0;
                                  int q = atomicAdd(&ecnt[lc+1], 1); if (q < CAP) cloc[lc+1][q] = row; }
                if (v.z != 0.f) { if (p0 < CAP) csr[(size_t)row*CAP+p0] = e0+lc+2; ++p0;
                                  int q = atomicAdd(&ecnt[lc+2], 1); if (q < CAP) cloc[lc+2][q] = row; }
                if (v.w != 0.f) { if (p0 < CAP) csr[(size_t)row*CAP+p0] = e0+lc+3; ++p0;
                                  int q = atomicAdd(&ecnt[lc+3], 1); if (q < CAP) cloc[lc+3][q] = row; }
            }
        }
    }
    __syncthreads();
    // copy member lists to global csc (for K2') + col_cnt
    for (int e = w; e < PNL; e += 16) {
        int cnt = ecnt[e]; if (cnt > CAP) cnt = CAP;
        if (lane == 0) col_cnt[e0 + e] = cnt;
        for (int i = lane; i < cnt; i += 64) csc[(size_t)(e0 + e) * CAP + i] = cloc[e][i];
    }
    // edge aggregation from LDS indices: wave w -> edges w*2, w*2+1
    const int half = lane >> 5, cl = lane & 31;
    const ushort* xb = x0b + cl * 8;
    #pragma unroll 1
    for (int ee = w * 2; ee < w * 2 + 2; ++ee) {
        int cnt = ecnt[ee]; if (cnt > CAP) cnt = CAP;
        float a0[8] = {}, a1[8] = {};
        int i = 0;
        for (; i + 4 <= cnt; i += 4) {               // 4 rows/iter (2 per half)
            int na = cloc[ee][i + half];             // LDS broadcast
            int nb = cloc[ee][i + 2 + half];
            u16x8 ra = *(const u16x8*)(xb + (size_t)na * CC);
            u16x8 rb = *(const u16x8*)(xb + (size_t)nb * CC);
            #pragma unroll
            for (int c = 0; c < 8; ++c) { a0[c] += b2f(ra[c]); a1[c] += b2f(rb[c]); }
        }
        if (i + 2 <= cnt) {
            int na = cloc[ee][i + half];
            u16x8 ra = *(const u16x8*)(xb + (size_t)na * CC);
            #pragma unroll
            for (int c = 0; c < 8; ++c) a0[c] += b2f(ra[c]);
            i += 2;
        }
        if (i < cnt && half == 0) {
            int na = cloc[ee][i];
            u16x8 ra = *(const u16x8*)(xb + (size_t)na * CC);
            #pragma unroll
            for (int c = 0; c < 8; ++c) a0[c] += b2f(ra[c]);
        }
        u16x8 r8;
        #pragma unroll
        for (int c = 0; c < 8; ++c) {
            float t = a0[c] + a1[c];
            t += __shfl_xor(t, 32);
            r8[c] = f2b(t);                          // raw (unscaled) bf16
        }
        if (half == 0) *(u16x8*)(m01s + (size_t)(e0 + ee) * CC + cl * 8) = r8;
    }
}

// ---- K2': er[e] = rsqrt( (sum of member degrees) / col_cnt[e] ) ------------
__global__ __launch_bounds__(256) void k2_er(const int* __restrict__ csc,
                                             const int* __restrict__ col_cnt,
                                             const int* __restrict__ row_cnt,
                                             float* __restrict__ er) {
    const int wave = threadIdx.x >> 6, lane = threadIdx.x & 63;
    const int e = blockIdx.x * 4 + wave;
    int cnt = col_cnt[e]; if (cnt > CAP) cnt = CAP;
    float s = 0.f;
    for (int i = lane; i < cnt; i += 64)
        s += (float)row_cnt[csc[(size_t)e * CAP + i]];
    #pragma unroll
    for (int d = 1; d < 64; d <<= 1) s += __shfl_xor(s, d);
    if (lane == 0) er[e] = rsqrtf(s / (float)cnt);
}

// ---- K5'': node aggregation (er-weighted) + skip + fused MFMA GEMM ----------
// Block = 16 nodes, 16 waves. Wave w gathers er[e]*m01s_raw[e] rows -> xc row
// in LDS (stride 264 -> free 2-way). Sync. Wave w computes
// out[0:16][w*16:(w+1)*16] = 0.5*xc + 0.5*xc@W^T via 8 MFMAs.
__global__ __launch_bounds__(1024, 8) void k5_fused(const ushort* __restrict__ x0b,
                                                    const ushort* __restrict__ m01s,
                                                    const int* __restrict__ csr,
                                                    const int* __restrict__ row_cnt,
                                                    const float* __restrict__ er,
                                                    const ushort* __restrict__ Wb,
                                                    float* __restrict__ out) {
    __shared__ __align__(16) ushort xs[16][264];
    const int w = threadIdx.x >> 6;
    const int lane = threadIdx.x & 63;
    const int half = lane >> 5;
    const int cl = lane & 31;
    const int n = blockIdx.x * 16 + w;
    const int cnt_true = row_cnt[n];
    const int cnt = cnt_true < CAP ? cnt_true : CAP;
    const float nr = rsqrtf((float)cnt_true);
    const int* ep = csr + (size_t)n * CAP;
    const int idx = ep[lane];
    const ushort* mb = m01s + cl * 8;
    float a0[8] = {}, a1[8] = {};
    const int lim = cnt < 64 ? cnt : 64;
    int i = 0;
    for (; i + 8 <= lim; i += 8) {
        int f0 = __shfl(idx, i + half);
        int f1 = __shfl(idx, i + 2 + half);
        int f2 = __shfl(idx, i + 4 + half);
        int f3 = __shfl(idx, i + 6 + half);
        float w0 = er[f0], w1 = er[f1], w2 = er[f2], w3 = er[f3];
        u16x8 r0 = *(const u16x8*)(mb + (size_t)f0 * CC);
        u16x8 r1 = *(const u16x8*)(mb + (size_t)f1 * CC);
        u16x8 r2 = *(const u16x8*)(mb + (size_t)f2 * CC);
        u16x8 r3 = *(const u16x8*)(mb + (size_t)f3 * CC);
        #pragma unroll
        for (int c = 0; c < 8; ++c) {
            a0[c] += w0 * b2f(r0[c]); a1[c] += w1 * b2f(r1[c]);
            a0[c] += w2 * b2f(r2[c]); a1[c] += w3 * b2f(r3[c]);
        }
    }
    for (; i + 2 <= lim; i += 2) {
        int f0 = __shfl(idx, i + half);
        float w0 = er[f0];
        u16x8 r0 = *(const u16x8*)(mb + (size_t)f0 * CC);
        #pragma unroll
        for (int c = 0; c < 8; ++c) a0[c] += w0 * b2f(r0[c]);
    }
    if (i < lim) {
        int f0 = __shfl(idx, i);
        if (half == 0) {
            float w0 = er[f0];
            u16x8 r0 = *(const u16x8*)(mb + (size_t)f0 * CC);
            #pragma unroll
            for (int c = 0; c < 8; ++c) a0[c] += w0 * b2f(r0[c]);
        }
    }
    if (cnt > 64 && half == 0) {                     // vanishing probability
        for (int j = 64; j < cnt; ++j) {
            int f0 = ep[j];
            float w0 = er[f0];
            u16x8 r0 = *(const u16x8*)(mb + (size_t)f0 * CC);
            #pragma unroll
            for (int c = 0; c < 8; ++c) a0[c] += w0 * b2f(r0[c]);
        }
    }
    u16x8 x = *(const u16x8*)(x0b + (size_t)n * CC + cl * 8);
    const float s = 0.9f * nr;
    u16x8 r8;
    #pragma unroll
    for (int c = 0; c < 8; ++c) {
        float t = a0[c] + a1[c];
        t += __shfl_xor(t, 32);
        r8[c] = f2b(s * t + 0.1f * b2f(x[c]));
    }
    if (half == 0) *(u16x8*)(&xs[w][cl * 8]) = r8;
    __syncthreads();
    // MFMA epilogue: A row=l&15, k=(l>>4)*8+e; B col=l&15; C/D col=l&15,
    // row=(l>>4)*4+reg (m89-verified).
    const int lr = lane & 15, lk = lane >> 4;
    const int n0 = w * 16;
    f32x4 acc = {0.f, 0.f, 0.f, 0.f};
    #pragma unroll
    for (int kb = 0; kb < 8; ++kb) {
        bf16x8 a = *(const bf16x8*)(&xs[lr][kb * 32 + lk * 8]);
        bf16x8 b = *(const bf16x8*)(Wb + (size_t)(n0 + lr) * CC + kb * 32 + lk * 8);
        acc = __builtin_amdgcn_mfma_f32_16x16x32_bf16(a, b, acc, 0, 0, 0);
    }
    const size_t rb = (size_t)blockIdx.x * 16;
    #pragma unroll
    for (int r = 0; r < 4; ++r) {
        int row = lk * 4 + r;
        int col = n0 + lr;
        float sk = b2f(xs[row][col]);
        out[(rb + row) * CC + col] = 0.5f * sk + 0.5f * acc[r];
    }
}

// ---- launch -----------------------------------------------------------------
extern "C" void kernel_launch(void* const* d_in, const int* in_sizes, int n_in,
                              void* d_out, int out_size, void* d_ws, size_t ws_size,
                              hipStream_t stream) {
    const float* x0 = (const float*)d_in[0];
    const float* B  = (const float*)d_in[1];
    const float* W  = (const float*)d_in[2];
    float* out = (float*)d_out;

    char* ws = (char*)d_ws;
    const size_t need = (16ull << 20) + (512ull << 10);
    if (ws_size < need) return;

    int*    csr     = (int*)(ws);                    // 4 MB
    int*    csc     = (int*)(ws + (4ull << 20));     // 4 MB
    ushort* m01s    = (ushort*)(ws + (8ull << 20));  // 4 MB (bf16, unscaled)
    ushort* x0b     = (ushort*)(ws + (12ull << 20)); // 4 MB (bf16)
    ushort* Wb      = (ushort*)(ws + (16ull << 20)); // 128 KB (bf16)
    int*    row_cnt = (int*)(ws + (16ull << 20) + (256u << 10)); // 32 KB
    int*    col_cnt = row_cnt + NN;                  // 32 KB
    float*  er      = (float*)(col_cnt + NE);        // 32 KB

    k0_convert<<<NN * CC / 8 / 256, 256, 0, stream>>>(x0, W, x0b, Wb, row_cnt);
    k1_panel<<<NE / PNL, 1024, 0, stream>>>(B, x0b, csr, row_cnt, col_cnt, csc, m01s);
    k2_er<<<NE / 4, 256, 0, stream>>>(csc, col_cnt, row_cnt, er);
    k5_fused<<<NN / 16, 1024, 0, stream>>>(x0b, m01s, csr, row_cnt, er, Wb, out);
}